// Round 15
// baseline (695.536 us; speedup 1.0000x reference)
//
#include <hip/hip_runtime.h>
#include <hip/hip_bf16.h>
#include <hip/hip_cooperative_groups.h>
#include <math.h>

namespace cg = cooperative_groups;

#define C_ 19
#define F_ 256
#define S_ 256
#define N_ 16384
#define M_ 9728
#define GEMM_TILES 4864   // 38 mt * 128 nt (r12 decode)
#define PREP_UNITS 424    // 256 A-conv + 152 B-conv + 16 zero

typedef __bf16 bf16_t;
typedef bf16_t bf16x8 __attribute__((ext_vector_type(8)));
typedef float floatx4 __attribute__((ext_vector_type(4)));

#define AS1 __attribute__((address_space(1)))
#define AS3 __attribute__((address_space(3)))

// Fragment-order layout (validated r5-r14): element (row, f) lives at
//   ((row>>4)*8 + (f>>5))*512 + ((f>>3)&3)*128 + (row&15)*8 + (f&7)
// fragment (16-row group g, k-step kt) = contiguous 1 KB at (g*8+kt)*512,
// ordered lane*8 with lane=(kchunk<<4)|row.
__device__ inline size_t fragoff(int row, int f) {
    return ((size_t)((row >> 4) * 8 + (f >> 5))) * 512
         + (size_t)((((f >> 3) & 3) * 128) + ((row & 15) * 8) + (f & 7));
}

// ---------------- the whole pipeline as one cooperative kernel ----------------
__global__ __launch_bounds__(512, 4) void k_all(const float* __restrict__ pred,
                                                const float* __restrict__ mem,
                                                const int* __restrict__ labels,
                                                const int* __restrict__ mask,
                                                const int* __restrict__ wmem,
                                                __hip_bfloat16* __restrict__ A16f,
                                                __hip_bfloat16* __restrict__ B16,
                                                float* __restrict__ total,
                                                __hip_bfloat16* __restrict__ classbuf,
                                                int* __restrict__ ctrl,
                                                float* __restrict__ out) {
    cg::grid_group grid = cg::this_grid();

    __shared__ __hip_bfloat16 As[128 * 256];     // 64 KB
    __shared__ float totals_s[4][128];
    __shared__ int lab_s[128];
    __shared__ float part[8][64];
    __shared__ float invf_s[64];
    __shared__ float csum_s[C_];
    __shared__ int ccnt_s[C_];

    float* class_sum = (float*)(ctrl + 1);
    int* class_cnt = ctrl + 20;

    int t = threadIdx.x, w = t >> 6, lane = t & 63;
    int nb = gridDim.x;

    // ================= phase A: prep (grid-stride over 424 units) =================
    for (int u = blockIdx.x; u < PREP_UNITS; u += nb) {
        if (u < 256) {
            // pred -> A16f (frag order, normalized bf16); 64 pixels, 8 f-chunks
            int b = u >> 6, hw0 = (u & 63) * 64;
            int j = t & 63, q = t >> 6;              // q 0..7
            int n0 = b * 4096 + hw0;
            const float* base = pred + ((size_t)(b * F_ + q * 32)) * 4096 + hw0 + j;
            float v[32];
            float s = 0.f;
            #pragma unroll
            for (int i = 0; i < 32; ++i) {
                float x = base[(size_t)i * 4096];
                v[i] = x;
                s += x * x;
            }
            part[q][j] = s;
            __syncthreads();
            if (t < 64) {
                float ss = 0.f;
                #pragma unroll
                for (int q2 = 0; q2 < 8; ++q2) ss += part[q2][t];
                invf_s[t] = 1.0f / sqrtf(ss);
            }
            __syncthreads();
            float invf = invf_s[j];
            #pragma unroll
            for (int c = 0; c < 4; ++c) {
                int f = q * 32 + c * 8;
                __hip_bfloat16 tmp[8];
                #pragma unroll
                for (int uu = 0; uu < 8; ++uu) tmp[uu] = __float2bfloat16(v[c * 8 + uu] * invf);
                *(float4*)&A16f[fragoff(n0 + j, f)] = *(float4*)tmp;
            }
            __syncthreads();                          // part[] reused next iteration
        } else if (u < 408) {
            // mem -> B16 (frag order, normalized bf16); 64 rows, wave = 8 rows
            int row0 = (u - 256) * 64 + w * 8;
            #pragma unroll
            for (int it = 0; it < 8; ++it) {
                int row = row0 + it;
                float4 a = ((const float4*)(mem + (size_t)row * F_))[lane];
                float s = a.x*a.x + a.y*a.y + a.z*a.z + a.w*a.w;
                #pragma unroll
                for (int off = 32; off; off >>= 1) s += __shfl_xor(s, off, 64);
                float invm = 1.0f / sqrtf(s);
                __hip_bfloat16 tmp[4];
                tmp[0] = __float2bfloat16(a.x * invm);
                tmp[1] = __float2bfloat16(a.y * invm);
                tmp[2] = __float2bfloat16(a.z * invm);
                tmp[3] = __float2bfloat16(a.w * invm);
                *(float2*)&B16[fragoff(row, lane * 4)] = *(float2*)tmp;
            }
        } else {
            // zero total[] (+ ctrl in unit 408)
            if (u == 408 && t < 40) ctrl[t] = 0;
            int idx = (((u - 408) << 9) + t) * 2;
            total[idx] = 0.f;
            total[idx + 1] = 0.f;
        }
    }
    __threadfence();
    grid.sync();

    // ================= phase B: GEMM (grid-stride, r12 decode & body) =================
    // tile % 8 == blockIdx % 8 (nb % 8 == 0) -> XCD clustering preserved.
    int nh = w & 1, mq = w >> 1;
    int colL = lane & 15, rgrp = (lane >> 4) * 4;
    for (int tile = blockIdx.x; tile < GEMM_TILES; tile += nb) {
        int xcd = tile & 7, jj = tile >> 3;
        int mt = jj >> 4;                            // 0..37
        int nt = ((jj & 15) << 3) | xcd;             // 0..127
        int n0 = nt * 128, m0 = mt * 256;

        if (t < 128) lab_s[t] = labels[n0 + t];
        __syncthreads();                             // prev tile fully done
        {
            const __hip_bfloat16* src = A16f + ((size_t)n0 << 8) + w * 4096 + lane * 8;
            __hip_bfloat16* dst = &As[w * 4096];
            #pragma unroll
            for (int i = 0; i < 8; ++i)
                __builtin_amdgcn_global_load_lds((const AS1 unsigned int*)(src + i * 512),
                                                 (AS3 unsigned int*)(dst + i * 512), 16, 0, 0);
        }
        __syncthreads();

        floatx4 acc[4][4];
        #pragma unroll
        for (int i = 0; i < 4; ++i)
            #pragma unroll
            for (int j2 = 0; j2 < 4; ++j2) acc[i][j2] = (floatx4){0.f, 0.f, 0.f, 0.f};

        const bf16x8* Bp = (const bf16x8*)B16 + ((size_t)((m0 >> 4) + mq * 4) * 8) * 64 + lane;

        #pragma unroll
        for (int kt = 0; kt < 8; ++kt) {
            bf16x8 af[4], bfr[4];
            #pragma unroll
            for (int ni = 0; ni < 4; ++ni)
                af[ni] = *(const bf16x8*)&As[((nh * 4 + ni) * 8 + kt) * 512 + lane * 8];
            #pragma unroll
            for (int mi = 0; mi < 4; ++mi)
                bfr[mi] = Bp[(size_t)(mi * 8 + kt) * 64];
            #pragma unroll
            for (int ni = 0; ni < 4; ++ni)
                #pragma unroll
                for (int mi = 0; mi < 4; ++mi)
                    acc[ni][mi] = __builtin_amdgcn_mfma_f32_16x16x32_bf16(af[ni], bfr[mi], acc[ni][mi], 0, 0, 0);
        }

        // epilogue: E = exp(2*cos); row sums + own-class bf16 scatter
        int cls = mt >> 1;
        int cib = (mt & 1) * 256 + mq * 64 + colL;
        float racc[4][4];
        #pragma unroll
        for (int ni = 0; ni < 4; ++ni)
            #pragma unroll
            for (int r = 0; r < 4; ++r) racc[ni][r] = 0.f;
        #pragma unroll
        for (int ni = 0; ni < 4; ++ni)
            #pragma unroll
            for (int r = 0; r < 4; ++r) {
                int row = nh * 64 + ni * 16 + rgrp + r;
                bool sel = (lab_s[row] == cls);
                size_t ebase = (size_t)(n0 + row) * 512 + cib;
                #pragma unroll
                for (int mi = 0; mi < 4; ++mi) {
                    float e = __expf(2.0f * acc[ni][mi][r]);
                    racc[ni][r] += e;
                    if (sel) classbuf[ebase + mi * 16] = __float2bfloat16(e);
                }
            }

        #pragma unroll
        for (int ni = 0; ni < 4; ++ni)
            #pragma unroll
            for (int r = 0; r < 4; ++r) {
                float s = racc[ni][r];
                s += __shfl_xor(s, 1, 64);
                s += __shfl_xor(s, 2, 64);
                s += __shfl_xor(s, 4, 64);
                s += __shfl_xor(s, 8, 64);
                if (colL == 0) totals_s[mq][nh * 64 + ni * 16 + rgrp + r] = s;
            }
        __syncthreads();
        if (t < 128)
            atomicAdd(&total[n0 + t],
                      totals_s[0][t] + totals_s[1][t] + totals_s[2][t] + totals_s[3][t]);
    }
    __threadfence();
    grid.sync();

    // ================= phase C: per-pixel terms (blocks >= 256 preferred) =============
    for (int u = (blockIdx.x + nb - 256) % nb; u < 256; u += nb) {
        if (t < C_) { csum_s[t] = 0.f; ccnt_s[t] = 0; }
        __syncthreads();
        int n0 = u * 64;
        for (int q = 0; q < 8; ++q) {
            int n = n0 + w * 8 + q;
            if (!mask[n]) continue;
            int wm = wmem[n];
            int lab = labels[n];
            bf16x8 ev = *(const bf16x8*)&classbuf[(size_t)n * 512 + lane * 8];
            float vv[8];
            #pragma unroll
            for (int uu = 0; uu < 8; ++uu) vv[uu] = (float)ev[uu];
            float bs = vv[0] + vv[1] + vv[2] + vv[3] + vv[4] + vv[5] + vv[6] + vv[7];
            #pragma unroll
            for (int off = 1; off < 64; off <<= 1) bs += __shfl_xor(bs, off, 64);
            float down = total[n] - bs;
            int lo = (wm == 1) ? 0 : 32;             // wm==1 -> first half [0,S)
            float ts = 0.f;
            if (lane >= lo && lane < lo + 32) {
                #pragma unroll
                for (int uu = 0; uu < 8; ++uu) {
                    float pv = vv[uu];
                    ts += -logf(pv / (pv + down + 1e-12f) + 1e-12f);
                }
            }
            #pragma unroll
            for (int off = 1; off < 64; off <<= 1) ts += __shfl_xor(ts, off, 64);
            if (lane == 0) {
                atomicAdd(&csum_s[lab], ts);
                atomicAdd(&ccnt_s[lab], 1);
            }
        }
        __syncthreads();
        if (t < C_ && ccnt_s[t] > 0) {
            atomicAdd(&class_sum[t], csum_s[t]);
            atomicAdd(&class_cnt[t], ccnt_s[t]);
        }
        __syncthreads();
    }
    __threadfence();
    grid.sync();

    // ================= final: one thread writes the loss =================
    if (blockIdx.x == 0 && t == 0) {
        float loss = 0.f, kc = 0.f;
        for (int c = 0; c < C_; ++c) {
            int cn = class_cnt[c];
            float sc = class_sum[c];
            if (cn > 0) { loss += sc / ((float)cn * (float)S_); kc += 1.f; }
        }
        out[0] = loss / fmaxf(kc, 1.f);
    }
}

extern "C" void kernel_launch(void* const* d_in, const int* in_sizes, int n_in,
                              void* d_out, int out_size, void* d_ws, size_t ws_size,
                              hipStream_t stream) {
    const float* mem    = (const float*)d_in[0];
    const float* pred   = (const float*)d_in[1];
    const int*   labels = (const int*)  d_in[2];
    const int*   mask   = (const int*)  d_in[3];
    const int*   wmem   = (const int*)  d_in[4];
    float* out = (float*)d_out;

    float* ws = (float*)d_ws;
    float* total = ws;                                // N_ floats (zeroed in-phase)
    int*   ctrl  = (int*)(ws + N_);                   // 40 words (zeroed in-phase)
    __hip_bfloat16* classbuf = (__hip_bfloat16*)(ws + 16424);    // 16.78 MB bf16
    __hip_bfloat16* A16f = (__hip_bfloat16*)(ws + 4210728);      // 8 MB (frag order)
    __hip_bfloat16* B16  = (__hip_bfloat16*)(ws + 6307880);      // 4.98 MB (frag order)

    void* args[] = {(void*)&pred, (void*)&mem, (void*)&labels, (void*)&mask,
                    (void*)&wmem, (void*)&A16f, (void*)&B16, (void*)&total,
                    (void*)&classbuf, (void*)&ctrl, (void*)&out};

    hipError_t e = hipLaunchCooperativeKernel((const void*)k_all, dim3(512), dim3(512),
                                              args, 0, stream);
    if (e != hipSuccess) {
        (void)hipGetLastError();                      // clear; retry at safe grid
        hipLaunchCooperativeKernel((const void*)k_all, dim3(256), dim3(512),
                                   args, 0, stream);
    }
}